// Round 1
// baseline (322.785 us; speedup 1.0000x reference)
//
#include <hip/hip_runtime.h>
#include <hip/hip_bf16.h>

#define TT 2048
#define BB 8
#define DD 128
#define HH 4
#define BT (BB*TT)
#define BH (BB*HH)
#define SCALE 0.1767766952966369f
#define S2LOG (SCALE * 1.4426950408889634f)   // scale * log2(e), folded at compile time

typedef __attribute__((ext_vector_type(8))) short short8;
typedef __attribute__((ext_vector_type(4))) short short4v;
typedef __attribute__((ext_vector_type(4))) float f32x4;
typedef __hip_bfloat16 bf16;

#define MFMA16(a,b,c) __builtin_amdgcn_mfma_f32_16x16x32_bf16(a,b,c,0,0,0)

static __device__ inline short8 ldg8(const bf16* p) {
  return *reinterpret_cast<const short8*>(p);
}
static __device__ inline short4v ldg4(const bf16* p) {
  return *reinterpret_cast<const short4v*>(p);
}
static __device__ inline float b2f(bf16 x) { return __bfloat162float(x); }
static __device__ inline short f2bs(float x) {
  bf16 h = __float2bfloat16(x);
  return *reinterpret_cast<short*>(&h);
}
// load 8 contiguous f32 from global, convert to bf16 A/B-fragment
static __device__ inline short8 ldcvt8(const float* p) {
  f32x4 f0 = *reinterpret_cast<const f32x4*>(p);
  f32x4 f1 = *reinterpret_cast<const f32x4*>(p + 4);
  short8 r;
  #pragma unroll
  for (int i = 0; i < 4; ++i) { r[i] = f2bs(f0[i]); r[4+i] = f2bs(f1[i]); }
  return r;
}
// pack V^T B-fragment with the permuted-k slot order: slot 8*lq+j  ->  k = 4*lq + (j<4 ? j : 12+j)
static __device__ inline short8 pack_v(const bf16* vp) {
  short4v lo = ldg4(vp);        // k = base + 4*lq + j
  short4v hi = ldg4(vp + 16);   // k = base + 16 + 4*lq + j
  short8 r;
  #pragma unroll
  for (int j = 0; j < 4; ++j) { r[j] = lo[j]; r[4+j] = hi[j]; }
  return r;
}

// ---------------- Kernel 1: MFMA projections (unchanged) ----------------
__global__ __launch_bounds__(256) void proj_kernel(
    const float* __restrict__ lob, const float* __restrict__ hawkes,
    const float* __restrict__ Wp, const float* __restrict__ bp,
    const float* __restrict__ Win, const float* __restrict__ binp,
    bf16* __restrict__ qg, bf16* __restrict__ kg, bf16* __restrict__ vtg) {
  __shared__ bf16 hT[32*136];
  __shared__ bf16 vT[128*40];
  int tid = threadIdx.x;
  int wave = tid >> 6, lane = tid & 63;
  int lr = lane & 15, lq = lane >> 4;
  int r0 = blockIdx.x * 32;
  int b  = r0 >> 11, t0 = r0 & 2047;
  f32x4 z = {0.f,0.f,0.f,0.f};

  short8 alob[2][4], ahk[2];
  #pragma unroll
  for (int mt = 0; mt < 2; ++mt) {
    const float* lp = lob + (size_t)(r0 + mt*16 + lr)*128;
    #pragma unroll
    for (int kt = 0; kt < 4; ++kt) alob[mt][kt] = ldcvt8(lp + kt*32 + lq*8);
    ahk[mt] = ldcvt8(hawkes + (size_t)(r0 + mt*16 + lr)*32 + lq*8);
  }

  for (int nt = wave; nt < 8; nt += 4) {
    int cn = nt*16;
    short8 bfrag = ldcvt8(Wp + (size_t)(cn + lr)*32 + lq*8);
    float bias = bp[cn + lr];
    #pragma unroll
    for (int mt = 0; mt < 2; ++mt) {
      f32x4 c = MFMA16(ahk[mt], bfrag, z);
      #pragma unroll
      for (int r = 0; r < 4; ++r)
        hT[(mt*16 + lq*4 + r)*136 + cn + lr] = __float2bfloat16(c[r] + bias);
    }
  }
  __syncthreads();

  short8 ah[2][4];
  #pragma unroll
  for (int mt = 0; mt < 2; ++mt)
    #pragma unroll
    for (int kt = 0; kt < 4; ++kt)
      ah[mt][kt] = *reinterpret_cast<const short8*>(&hT[(mt*16 + lr)*136 + kt*32 + lq*8]);

  for (int nt = wave; nt < 24; nt += 4) {
    int which = nt >> 3;
    int c = (nt & 7)*16 + lr;
    const float* wrow = Win + (size_t)(which*128 + c)*128;
    float bias = binp[which*128 + c];
    f32x4 acc0 = z, acc1 = z;
    #pragma unroll
    for (int kt = 0; kt < 4; ++kt) {
      short8 bfrag = ldcvt8(wrow + kt*32 + lq*8);
      if (which == 0) {
        acc0 = MFMA16(alob[0][kt], bfrag, acc0);
        acc1 = MFMA16(alob[1][kt], bfrag, acc1);
      } else {
        acc0 = MFMA16(ah[0][kt], bfrag, acc0);
        acc1 = MFMA16(ah[1][kt], bfrag, acc1);
      }
    }
    int head = c >> 5, dd = c & 31;
    #pragma unroll
    for (int mt = 0; mt < 2; ++mt) {
      f32x4 acc = mt ? acc1 : acc0;
      #pragma unroll
      for (int r = 0; r < 4; ++r) {
        int row = mt*16 + lq*4 + r;
        float val = acc[r] + bias;
        if (which == 0)
          qg[((size_t)(b*HH + head)*TT + t0 + row)*32 + dd] = __float2bfloat16(val);
        else if (which == 1)
          kg[((size_t)(b*HH + head)*TT + t0 + row)*32 + dd] = __float2bfloat16(val);
        else
          vT[c*40 + row] = __float2bfloat16(val);
      }
    }
  }
  __syncthreads();

  {
    int dd = tid >> 1, half = tid & 1;
    int bh = b*HH + (dd >> 5);
    short8 s0 = *reinterpret_cast<const short8*>(&vT[dd*40 + half*16]);
    short8 s1 = *reinterpret_cast<const short8*>(&vT[dd*40 + half*16 + 8]);
    bf16* dst = vtg + ((size_t)bh*32 + (dd & 31))*TT + t0 + half*16;
    *reinterpret_cast<short8*>(dst) = s0;
    *reinterpret_cast<short8*>(dst + 8) = s1;
  }
}

// ---------------- Kernel 2: fused attention ----------------
// Pass 1 (swapped QK^T): per-lane row sums -> denominators, 2-shuffle reduce.
// Pass 2: swapped QK^T -> exp2(fma(s,S2,-log2 l)) -> P in registers.
//   P -> LDS (vector b128, stride 68, bank-uniform) ONLY for the cross-head
//   attn_w mean. PV uses P fragments straight from registers with a
//   k-permutation applied identically to the V^T B-fragment (bijection ->
//   result exact). Double-buffered plds: ONE barrier per 64-k tile.
__global__ __launch_bounds__(256) void attn_kernel(const bf16* __restrict__ qg,
    const bf16* __restrict__ kg, const bf16* __restrict__ vtg,
    float* __restrict__ attn_out, float* __restrict__ ctxg) {
  // XCD swizzle: 512 blocks = 8 XCDs x 64; each XCD owns one batch b.
  int wg = (blockIdx.x & 7)*64 + (blockIdx.x >> 3);
  int b = wg >> 6, qt = wg & 63;
  int head = threadIdx.x >> 6, lane = threadIdx.x & 63;
  int lr = lane & 15, lq = lane >> 4;
  int bh = b*HH + head;
  __shared__ float plds[2][4][32*68];   // [buf][head][q(32) x k(64), stride 68]
  const bf16* qp = qg + ((size_t)(bh*TT) + qt*32)*32;
  const bf16* kb = kg + (size_t)(bh*TT)*32;
  const bf16* vb = vtg + (size_t)(bh*32)*TT;
  short8 a0 = ldg8(qp + lr*32 + lq*8);        // Q rows 0-15  (B-frag of Q^T)
  short8 a1 = ldg8(qp + (16+lr)*32 + lq*8);   // Q rows 16-31
  f32x4 z = {0.f,0.f,0.f,0.f};

  // ---- pass 1: softmax denominators. S^T = MFMA(K_frag, Q_frag):
  // lane holds S[q=lr][k=lq*4+r]; accumulate exp, reduce over lq.
  float rs0 = 0.f, rs1 = 0.f;
  for (int kt = 0; kt < 64; ++kt) {
    const bf16* kp = kb + (size_t)(kt*32)*32;
    short8 bk0 = ldg8(kp + lr*32 + lq*8);
    short8 bk1 = ldg8(kp + (16+lr)*32 + lq*8);
    f32x4 s0a = MFMA16(bk0, a0, z);
    f32x4 s0b = MFMA16(bk0, a1, z);
    f32x4 s1a = MFMA16(bk1, a0, z);
    f32x4 s1b = MFMA16(bk1, a1, z);
    #pragma unroll
    for (int r = 0; r < 4; ++r) {
      rs0 += exp2f(s0a[r]*S2LOG) + exp2f(s1a[r]*S2LOG);
      rs1 += exp2f(s0b[r]*S2LOG) + exp2f(s1b[r]*S2LOG);
    }
  }
  rs0 += __shfl_xor(rs0, 16, 64); rs0 += __shfl_xor(rs0, 32, 64);
  rs1 += __shfl_xor(rs1, 16, 64); rs1 += __shfl_xor(rs1, 32, 64);
  float lb0 = -log2f(rs0);   // per-lane: denominator for q = qt*32 + lr
  float lb1 = -log2f(rs1);   // q = qt*32 + 16 + lr

  // ---- pass 2 ----
  f32x4 acc00 = z, acc01 = z, acc10 = z, acc11 = z;
  short8 kf[2][4];      // [buf][k16-subtile]   A-frags of K
  short8 vf[2][4];      // [buf][t32*2+dt]      permuted B-frags of V^T
  #pragma unroll
  for (int s = 0; s < 4; ++s)
    kf[0][s] = ldg8(kb + (size_t)(s*16 + lr)*32 + lq*8);
  #pragma unroll
  for (int t32 = 0; t32 < 2; ++t32)
    #pragma unroll
    for (int dt = 0; dt < 2; ++dt)
      vf[0][t32*2+dt] = pack_v(vb + (size_t)(dt*16 + lr)*TT + t32*32 + lq*4);

  int rr = (int)threadIdx.x >> 3, c0 = ((int)threadIdx.x & 7)*8;
  float* awdst = attn_out + ((size_t)(b*TT + qt*32 + rr))*TT + c0;

  for (int kt0 = 0; kt0 < 32; kt0 += 2) {
    #pragma unroll
    for (int par = 0; par < 2; ++par) {
      int kt2 = kt0 + par;
      int kbase = kt2*64;
      // prefetch next 64-k tile into the other register buffer
      if (kt2 < 31) {
        int nb = kbase + 64;
        #pragma unroll
        for (int s = 0; s < 4; ++s)
          kf[par^1][s] = ldg8(kb + (size_t)(nb + s*16 + lr)*32 + lq*8);
        #pragma unroll
        for (int t32 = 0; t32 < 2; ++t32)
          #pragma unroll
          for (int dt = 0; dt < 2; ++dt)
            vf[par^1][t32*2+dt] = pack_v(vb + (size_t)(dt*16 + lr)*TT + nb + t32*32 + lq*4);
      }
      // scores + exp + normalized-P: lane holds P[q=lr][k = s*16 + lq*4 + r]
      short8 ap[2][2];   // [qtile][t32]  A-frags of P (permuted-k slot order)
      #pragma unroll
      for (int qtile = 0; qtile < 2; ++qtile) {
        float lb = qtile ? lb1 : lb0;
        const short8& aq = qtile ? a1 : a0;
        #pragma unroll
        for (int s = 0; s < 4; ++s) {
          f32x4 sv = MFMA16(kf[par][s], aq, z);
          f32x4 p4;
          #pragma unroll
          for (int r = 0; r < 4; ++r) p4[r] = exp2f(fmaf(sv[r], S2LOG, lb));
          *reinterpret_cast<f32x4*>(
              &plds[par][head][(qtile*16 + lr)*68 + s*16 + lq*4]) = p4;
          #pragma unroll
          for (int r = 0; r < 4; ++r)
            ap[qtile][s>>1][(s&1)*4 + r] = f2bs(p4[r]);
        }
      }
      __syncthreads();
      // attn_w = mean over heads (only use of plds)
      {
        const float* p0 = &plds[par][0][rr*68 + c0];
        f32x4 u0 = *reinterpret_cast<const f32x4*>(p0);
        f32x4 u1 = *reinterpret_cast<const f32x4*>(p0 + 4);
        #pragma unroll
        for (int h = 1; h < 4; ++h) {
          const float* ph = &plds[par][h][rr*68 + c0];
          u0 += *reinterpret_cast<const f32x4*>(ph);
          u1 += *reinterpret_cast<const f32x4*>(ph + 4);
        }
        float* dst = awdst + kbase;
        *reinterpret_cast<f32x4*>(dst)     = u0 * 0.25f;
        *reinterpret_cast<f32x4*>(dst + 4) = u1 * 0.25f;
      }
      // PV straight from registers (same k-permutation on both operands)
      #pragma unroll
      for (int t32 = 0; t32 < 2; ++t32) {
        acc00 = MFMA16(ap[0][t32], vf[par][t32*2+0], acc00);
        acc01 = MFMA16(ap[0][t32], vf[par][t32*2+1], acc01);
        acc10 = MFMA16(ap[1][t32], vf[par][t32*2+0], acc10);
        acc11 = MFMA16(ap[1][t32], vf[par][t32*2+1], acc11);
      }
    }
  }
  #pragma unroll
  for (int r = 0; r < 4; ++r) {
    int row0 = lq*4 + r, row1 = row0 + 16;
    size_t base0 = ((size_t)(b*TT + qt*32 + row0))*128 + head*32;
    size_t base1 = ((size_t)(b*TT + qt*32 + row1))*128 + head*32;
    ctxg[base0 + lr]      = acc00[r];
    ctxg[base0 + 16 + lr] = acc01[r];
    ctxg[base1 + lr]      = acc10[r];
    ctxg[base1 + 16 + lr] = acc11[r];
  }
}

// ---------------- Kernel 3: out-proj + residual + LayerNorm -----------------
__global__ __launch_bounds__(256) void outln_kernel(const float* __restrict__ ctxg,
    const float* __restrict__ lob, const float* __restrict__ Wo,
    const float* __restrict__ bo, const float* __restrict__ gamma,
    const float* __restrict__ beta, float* __restrict__ outg) {
  __shared__ float sWo[128*132];    // [c][d] row-major, stride 132 (16B-aligned)
  __shared__ float sP[384];
  __shared__ float sCtx[4][128];
  __shared__ float sLob[4][128];
  int tid = threadIdx.x;
  for (int i = tid; i < 128*32; i += 256) {
    int c = i >> 5, d4 = (i & 31)*4;
    *reinterpret_cast<f32x4*>(&sWo[c*132 + d4]) =
        *reinterpret_cast<const f32x4*>(&Wo[(size_t)c*128 + d4]);
  }
  if (tid < 128) {
    sP[tid] = bo[tid]; sP[128+tid] = gamma[tid]; sP[256+tid] = beta[tid];
  }
  __syncthreads();
  int wave = tid >> 6, lane = tid & 63;
  for (int it = 0; it < 8; ++it) {
    int row = blockIdx.x*32 + it*4 + wave;
    const float* cg = ctxg + (size_t)row*128;
    const float* lg = lob + (size_t)row*128;
    // each wave stages + reads only its own rows: no barrier needed
    sCtx[wave][lane]    = cg[lane];
    sCtx[wave][64+lane] = cg[64+lane];
    sLob[wave][lane]    = lg[lane];
    sLob[wave][64+lane] = lg[64+lane];
    float x0 = sP[lane] + sLob[wave][lane];
    float x1 = sP[64+lane] + sLob[wave][64+lane];
    const float* w0 = &sWo[lane*132];
    const float* w1 = &sWo[(64+lane)*132];
    const float* cx = sCtx[wave];
    #pragma unroll 8
    for (int d4 = 0; d4 < 32; ++d4) {
      f32x4 cv  = *reinterpret_cast<const f32x4*>(cx + d4*4);
      f32x4 wv0 = *reinterpret_cast<const f32x4*>(w0 + d4*4);
      f32x4 wv1 = *reinterpret_cast<const f32x4*>(w1 + d4*4);
      x0 += cv[0]*wv0[0] + cv[1]*wv0[1] + cv[2]*wv0[2] + cv[3]*wv0[3];
      x1 += cv[0]*wv1[0] + cv[1]*wv1[1] + cv[2]*wv1[2] + cv[3]*wv1[3];
    }
    float sum = x0 + x1;
    #pragma unroll
    for (int m = 1; m < 64; m <<= 1) sum += __shfl_xor(sum, m, 64);
    float mu = sum * (1.0f/128.0f);
    float d0 = x0 - mu, d1 = x1 - mu;
    float vs = d0*d0 + d1*d1;
    #pragma unroll
    for (int m = 1; m < 64; m <<= 1) vs += __shfl_xor(vs, m, 64);
    float rstd = rsqrtf(vs*(1.0f/128.0f) + 1e-5f);
    outg[(size_t)row*128 + lane]      = d0*rstd*sP[128+lane] + sP[256+lane];
    outg[(size_t)row*128 + 64 + lane] = d1*rstd*sP[192+lane] + sP[320+lane];
  }
}

extern "C" void kernel_launch(void* const* d_in, const int* in_sizes, int n_in,
                              void* d_out, int out_size, void* d_ws, size_t ws_size,
                              hipStream_t stream) {
  const float* lob    = (const float*)d_in[0];
  const float* hawkes = (const float*)d_in[1];
  const float* Wp     = (const float*)d_in[2];
  const float* bp     = (const float*)d_in[3];
  const float* Win    = (const float*)d_in[4];
  const float* binp   = (const float*)d_in[5];
  const float* Wo     = (const float*)d_in[6];
  const float* bo     = (const float*)d_in[7];
  const float* gamma  = (const float*)d_in[8];
  const float* beta   = (const float*)d_in[9];
  float* outg = (float*)d_out;
  float* attn_out = outg + (size_t)BT*128;   // out (B,T,128) then attn_w (B,T,T)

  char* ws = (char*)d_ws;
  bf16*  qg   = (bf16*)(ws);                                   // 4 MB
  bf16*  kg   = (bf16*)(ws + (size_t)4*1024*1024);             // 4 MB
  bf16*  vtg  = (bf16*)(ws + (size_t)8*1024*1024);             // 4 MB (B,H,32,T)
  float* ctxg = (float*)(ws + (size_t)12*1024*1024);           // 8 MB

  proj_kernel<<<BT/32, 256, 0, stream>>>(lob, hawkes, Wp, bp, Win, binp, qg, kg, vtg);
  attn_kernel<<<BB*(TT/32), 256, 0, stream>>>(qg, kg, vtg, attn_out, ctxg);
  outln_kernel<<<512, 256, 0, stream>>>(ctxg, lob, Wo, bo, gamma, beta, outg);
}